// Round 14
// baseline (367.419 us; speedup 1.0000x reference)
//
#include <hip/hip_runtime.h>
#include <hip/hip_bf16.h>
#include <math.h>

#define NHEADS 10

typedef unsigned short ushort_t;
typedef unsigned int uint_t;

typedef __attribute__((ext_vector_type(4))) float f32x4;
typedef __attribute__((ext_vector_type(8))) short short8;

__device__ __forceinline__ float bu2f(ushort_t u){ return __uint_as_float(((uint_t)u)<<16); }
__device__ __forceinline__ ushort_t f2bu(float f){
    uint_t b = __float_as_uint(f);
    return (ushort_t)((b + 0x7FFFu + ((b>>16)&1u)) >> 16);   // RNE
}

// ---------------- CSR build ----------------
__global__ void k_count(const int* eidx, int E, int N, int* cnt){
    int e = blockIdx.x*blockDim.x + threadIdx.x;
    int ET = E + N;
    if(e >= ET) return;
    int d = (e < E) ? eidx[E + e] : (e - E);
    atomicAdd(&cnt[d], 1);
}

__global__ void k_scan(int* cnt, int N, int ET, int* indptr){
    __shared__ int lds[1024];
    int t = threadIdx.x;
    int chunk = (N + 1023)/1024;
    int base = t*chunk;
    int s = 0;
    for(int i=0;i<chunk;i++){ int idx=base+i; if(idx<N) s += cnt[idx]; }
    lds[t]=s;
    __syncthreads();
    for(int off=1; off<1024; off<<=1){
        int v = (t>=off)? lds[t-off] : 0;
        __syncthreads();
        lds[t]+=v;
        __syncthreads();
    }
    int run = lds[t]-s;
    for(int i=0;i<chunk;i++){
        int idx=base+i;
        if(idx<N){
            int c = cnt[idx];
            indptr[idx]=run;
            cnt[idx]=run;
            run += c;
        }
    }
    if(t==0) indptr[N]=ET;
}

__global__ void k_fill(const int* eidx, int E, int N, int* cursor, int* srcs){
    int e = blockIdx.x*blockDim.x + threadIdx.x;
    int ET = E + N;
    if(e >= ET) return;
    int s, d;
    if(e < E){ s = eidx[e]; d = eidx[E+e]; } else { s = e-E; d = e-E; }
    int pos = atomicAdd(&cursor[d], 1);
    srcs[pos] = s;
}

// wave-parallel bitonic sort + src-range boundary extraction (8 ranges of src-space)
__global__ void k_sortw(const int* indptr, int* srcs, int* rng, int N){
    int wid  = (blockIdx.x*blockDim.x + threadIdx.x) >> 6;
    int lane = threadIdx.x & 63;
    if(wid >= N) return;
    int p0 = indptr[wid], p1 = indptr[wid+1];
    int deg = p1 - p0;
    int win = (N + 7) >> 3;
    if(deg <= 64){
        int v = (lane < deg && deg > 1) ? srcs[p0+lane] : 0x7FFFFFFF;
        if(deg == 1 && lane == 0) v = srcs[p0];
        if(deg > 1){
            #pragma unroll
            for(int k=2; k<=64; k<<=1){
                #pragma unroll
                for(int j=k>>1; j>0; j>>=1){
                    int partner = __shfl_xor(v, j, 64);
                    bool dir   = ((lane & k) == 0);
                    bool small = ((lane & j) == 0);
                    int mn = min(v, partner), mx = max(v, partner);
                    v = (dir == small) ? mn : mx;
                }
            }
            if(lane < deg) srcs[p0+lane] = v;
        }
        // range starts: rng[wid*8+r] = p0 + #(src < r*win)
        #pragma unroll
        for(int r=0; r<8; r++){
            unsigned long long m = __ballot(v < r*win);
            if(lane == 0) rng[wid*8 + r] = p0 + (int)__popcll(m);
        }
    } else if(lane == 0){               // fallback, statistically never
        for(int i=p0+1;i<p1;i++){
            int v2 = srcs[i]; int j=i-1;
            while(j>=p0 && srcs[j]>v2){ srcs[j+1]=srcs[j]; j--; }
            srcs[j+1]=v2;
        }
        for(int r=0;r<8;r++){
            int b=r*win, c=0;
            for(int i=p0;i<p1;i++) if(srcs[i]<b) c++;
            rng[wid*8+r]=p0+c;
        }
    }
}

// ---------------- all weight transposes in one dispatch ----------------
__global__ void k_trans_all(const float* __restrict__ W1c,const float* __restrict__ W2c,
                            const float* __restrict__ W3c,const float* __restrict__ W4c,
                            ushort_t* T1,ushort_t* T2,ushort_t* T3,ushort_t* T4){
    int idx = blockIdx.x*blockDim.x + threadIdx.x;
    if(idx < 10240){ int c=idx/32, k=idx%32; T1[idx] = (k<16)? f2bu(W1c[(size_t)k*320+c]) : (ushort_t)0; return; }
    idx -= 10240;
    if(idx < 20480){ int c=idx/32, k=idx%32; T2[idx] = f2bu(W2c[(size_t)k*640+c]); return; }
    idx -= 20480;
    if(idx < 81920){ int c=idx/64, k=idx%64; T3[idx] = f2bu(W3c[(size_t)k*1280+c]); return; }
    idx -= 81920;
    if(idx < 32768){ int c=idx/128, k=idx%128; T4[idx] = f2bu(W4c[(size_t)k*256+c]); return; }
}

// ---------------- fc0: [N,24]@[24,16]+b, ELU ----------------
__global__ void k_fc0(const float* x, const float* W0, const float* b0, float* out, int N){
    int idx = blockIdx.x*blockDim.x+threadIdx.x;
    if(idx >= N*16) return;
    int n = idx>>4, c = idx&15;
    float acc = b0[c];
    #pragma unroll
    for(int k=0;k<24;k++) acc += x[n*24+k] * W0[k*16+c];
    out[idx] = acc>0.f ? acc : expm1f(acc);
}

// ---------------- LDS-free MFMA GEMM (verified R11/R12) ----------------
template<int K, int KP, int EPI, int OUTBF16>
__global__ void __launch_bounds__(256, 4)
k_gemm(const float* __restrict__ A, const ushort_t* __restrict__ BT,
       const float* __restrict__ bias, void* __restrict__ Cmat,
       int N, int HC){
    int t = threadIdx.x;
    int w = t >> 6, lane = t & 63;
    int lr = lane & 15, lk = lane >> 4;
    int row0 = blockIdx.x*64, col0 = blockIdx.y*64;
    int row = row0 + w*16 + lr;

    f32x4 acc[4];
    #pragma unroll
    for(int f=0; f<4; f++) acc[f] = (f32x4){0.f,0.f,0.f,0.f};

    #pragma unroll
    for(int kb = 0; kb < K; kb += 32){
        int k0 = kb + lk*8;
        short8 af = {0,0,0,0,0,0,0,0};
        if(row < N && k0 < K){
            const float* ap = &A[(size_t)row*K + k0];
            float4 a0 = *(const float4*)ap;
            float4 a1 = *(const float4*)(ap + 4);
            af[0]=(short)f2bu(a0.x); af[1]=(short)f2bu(a0.y);
            af[2]=(short)f2bu(a0.z); af[3]=(short)f2bu(a0.w);
            af[4]=(short)f2bu(a1.x); af[5]=(short)f2bu(a1.y);
            af[6]=(short)f2bu(a1.z); af[7]=(short)f2bu(a1.w);
        }
        #pragma unroll
        for(int f=0; f<4; f++){
            int col = col0 + f*16 + lr;
            short8 bf = *(const short8*)&BT[(size_t)col*KP + k0];
            acc[f] = __builtin_amdgcn_mfma_f32_16x16x32_bf16(af, bf, acc[f], 0, 0, 0);
        }
    }

    #pragma unroll
    for(int f=0; f<4; f++){
        #pragma unroll
        for(int j=0; j<4; j++){
            int r = row0 + w*16 + lk*4 + j;
            if(r >= N) continue;
            int col = col0 + f*16 + lr;
            float v = acc[f][j];
            if(EPI){
                v += bias[col];
                v = v>0.f ? v : expm1f(v);
            }
            if(OUTBF16) ((ushort_t*)Cmat)[(size_t)r*HC + col] = f2bu(v);
            else        ((float*)Cmat)[(size_t)r*HC + col] = v;
        }
    }
}

// ---------------- attention logits: 4 threads per (n,h) ----------------
template<int C>
__global__ void k_attn(const ushort_t* hf, const float* a_s, const float* a_d,
                       float* es, float* ed, int N){
    int tid = blockIdx.x*blockDim.x + threadIdx.x;
    if(tid >= N*NHEADS*4) return;
    int q   = tid & 3;
    int idx = tid >> 2;
    int n = idx/NHEADS, h = idx%NHEADS;
    constexpr int CQ = C/4;
    const ushort_t* hp = hf + (size_t)n*NHEADS*C + h*C + q*CQ;
    const float* asp = a_s + h*C + q*CQ;
    const float* adp = a_d + h*C + q*CQ;
    float s=0.f, d=0.f;
    #pragma unroll
    for(int cb=0; cb<CQ/8; cb++){
        uint4 qv = *(const uint4*)(hp + cb*8);
        uint_t uu[4] = {qv.x, qv.y, qv.z, qv.w};
        #pragma unroll
        for(int j=0;j<4;j++){
            float f0 = __uint_as_float(uu[j]<<16);
            float f1 = __uint_as_float(uu[j] & 0xFFFF0000u);
            int c = cb*8 + j*2;
            s += f0*asp[c] + f1*asp[c+1];
            d += f0*adp[c] + f1*adp[c+1];
        }
    }
    s += __shfl_xor(s, 1, 64); s += __shfl_xor(s, 2, 64);
    d += __shfl_xor(d, 1, 64); d += __shfl_xor(d, 2, 64);
    if(q == 0){ es[idx]=s; ed[idx]=d; }
}

// ---------------- W: per-node normalized softmax weights -> wbuf ----------------
// wave per node, 4 nodes/block. w = exp(leaky(es[src]+ed)) (no-max variant, verified R11);
// den via LDS serial adds; then scale wbuf in place.
__global__ void __launch_bounds__(256, 4)
k_wts(const int* __restrict__ indptr, const int* __restrict__ srcs,
      const float* __restrict__ es, const float* __restrict__ ed,
      float* __restrict__ wbuf, int N)
{
    __shared__ float wl4[4][64*NHEADS];
    __shared__ float stat[4][NHEADS];
    __shared__ int   degs[4];
    int wslot = threadIdx.x >> 6;
    int lane  = threadIdx.x & 63;
    int n = (blockIdx.x << 2) + wslot;
    bool valid = (n < N);
    int p0 = 0, deg = 0;
    if(valid){ p0 = indptr[n]; deg = indptr[n+1] - p0; }
    if(lane == 0) degs[wslot] = deg;
    __syncthreads();
    int maxdeg = max(max(degs[0],degs[1]), max(degs[2],degs[3]));
    int nch = (maxdeg + 63) >> 6;
    float* wl = wl4[wslot];

    int e6 = lane/10, h6 = lane%10;
    float edv = (valid && lane < 60) ? ed[n*NHEADS + h6] : 0.f;

    float den = 0.f;
    for(int c = 0; c < nch; c++){
        int base = c << 6;
        int lim = deg - base; if(lim > 64) lim = 64;
        if(valid && lane < 60){
            for(int i = e6; i < lim; i += 6){
                float v = es[(size_t)srcs[p0+base+i]*NHEADS + h6] + edv;
                v = (v >= 0.f) ? v : 0.2f*v;
                float wv = expf(fminf(v, 60.f));
                wl[i*NHEADS + h6] = wv;
                wbuf[(size_t)(p0+base+i)*NHEADS + h6] = wv;
            }
        }
        __syncthreads();
        if(valid && lane < NHEADS){
            for(int i = 0; i < lim; i++) den += wl[i*NHEADS + lane];
        }
        __syncthreads();
    }
    if(valid && lane < NHEADS) stat[wslot][lane] = 1.f/(den + 1e-30f);
    __syncthreads();
    if(valid && lane < 60){
        float dv = stat[wslot][h6];
        for(int i = e6; i < deg; i += 6)
            wbuf[(size_t)(p0+i)*NHEADS + h6] *= dv;
    }
}

// ---------------- G: XCD-affine range-partial gather ----------------
// wave = (node, src-range r). r = blockIdx.x % 8 rides round-robin block->XCD mapping,
// so XCD r only reads hf rows in window r (~hf/8, fits 4MB L2). Partials bf16, no atomics.
template<int C>
__global__ void __launch_bounds__(256, 4)
k_gath(const int* __restrict__ indptr, const int* __restrict__ srcs,
       const int* __restrict__ rng, const float* __restrict__ wbuf,
       const ushort_t* __restrict__ hf, ushort_t* __restrict__ part, int N)
{
    constexpr int TPN = C/8;
    constexpr int EG  = 64/TPN;
    int wslot = threadIdx.x >> 6;
    int lane  = threadIdx.x & 63;
    int r = blockIdx.x & 7;
    int n = (blockIdx.x >> 3)*4 + wslot;
    if(n >= N) return;
    int lo = rng[n*8 + r];
    int hi = (r < 7) ? rng[n*8 + r + 1] : indptr[n+1];
    int local = lane % TPN, eg = lane / TPN;
    int c8 = local*8;
    float acc[8];
    #pragma unroll
    for(int i=0;i<8;i++) acc[i]=0.f;
    for(int p = lo + eg; p < hi; p += EG){
        int s = srcs[p];
        const ushort_t* hp = hf + (size_t)s*NHEADS*C + c8;
        const float* wp = wbuf + (size_t)p*NHEADS;
        #pragma unroll
        for(int h=0;h<NHEADS;h++){
            uint4 q = *(const uint4*)(hp + h*C);
            float wd = wp[h];
            acc[0] += wd * __uint_as_float(q.x<<16);
            acc[1] += wd * __uint_as_float(q.x & 0xFFFF0000u);
            acc[2] += wd * __uint_as_float(q.y<<16);
            acc[3] += wd * __uint_as_float(q.y & 0xFFFF0000u);
            acc[4] += wd * __uint_as_float(q.z<<16);
            acc[5] += wd * __uint_as_float(q.z & 0xFFFF0000u);
            acc[6] += wd * __uint_as_float(q.w<<16);
            acc[7] += wd * __uint_as_float(q.w & 0xFFFF0000u);
        }
    }
    #pragma unroll
    for(int s = TPN; s < 64; s <<= 1){
        #pragma unroll
        for(int i=0;i<8;i++) acc[i] += __shfl_xor(acc[i], s, 64);
    }
    if(eg == 0){
        uint4 u;
        u.x = (uint_t)f2bu(acc[0]) | ((uint_t)f2bu(acc[1])<<16);
        u.y = (uint_t)f2bu(acc[2]) | ((uint_t)f2bu(acc[3])<<16);
        u.z = (uint_t)f2bu(acc[4]) | ((uint_t)f2bu(acc[5])<<16);
        u.w = (uint_t)f2bu(acc[6]) | ((uint_t)f2bu(acc[7])<<16);
        *(uint4*)&part[((size_t)r*N + n)*C + c8] = u;
    }
}

// ---------------- R: reduce 8 partials + mean + bias + ELU ----------------
template<int C>
__global__ void k_red(const ushort_t* __restrict__ part, const float* __restrict__ bc,
                      float* __restrict__ out, int N){
    int tid = blockIdx.x*blockDim.x + threadIdx.x;
    if(tid >= N*(C/8)) return;
    int n = tid/(C/8);
    int c8 = (tid%(C/8))*8;
    float s[8];
    #pragma unroll
    for(int i=0;i<8;i++) s[i]=0.f;
    #pragma unroll
    for(int r=0;r<8;r++){
        uint4 u = *(const uint4*)&part[((size_t)r*N + n)*C + c8];
        s[0] += __uint_as_float(u.x<<16);
        s[1] += __uint_as_float(u.x & 0xFFFF0000u);
        s[2] += __uint_as_float(u.y<<16);
        s[3] += __uint_as_float(u.y & 0xFFFF0000u);
        s[4] += __uint_as_float(u.z<<16);
        s[5] += __uint_as_float(u.z & 0xFFFF0000u);
        s[6] += __uint_as_float(u.w<<16);
        s[7] += __uint_as_float(u.w & 0xFFFF0000u);
    }
    float4 v0, v1;
    #pragma unroll
    for(int i=0;i<8;i++){
        float v = s[i]*(1.f/NHEADS) + bc[c8+i];
        v = v>0.f ? v : expm1f(v);
        if(i<4) ((float*)&v0)[i] = v; else ((float*)&v1)[i-4] = v;
    }
    *(float4*)&out[(size_t)n*C + c8]     = v0;
    *(float4*)&out[(size_t)n*C + c8 + 4] = v1;
}

// ---------------- head: logits 256->24 + log_softmax ----------------
__global__ void k_head(const float* hin, const float* W2, const float* b2v, float* out, int N){
    int grp  = threadIdx.x/32;
    int lane = threadIdx.x%32;
    int n = blockIdx.x*8 + grp;
    if(n>=N) return;
    float acc = -1e30f;
    if(lane < 24){
        acc = b2v[lane];
        for(int k=0;k<256;k++) acc += hin[n*256+k]*W2[k*24+lane];
    }
    float mx = acc;
    for(int off=16; off; off>>=1) mx = fmaxf(mx, __shfl_xor(mx, off, 32));
    float ex = (lane<24)? expf(acc-mx) : 0.f;
    float sm = ex;
    for(int off=16; off; off>>=1) sm += __shfl_xor(sm, off, 32);
    if(lane<24) out[n*24+lane] = acc - mx - logf(sm);
}

extern "C" void kernel_launch(void* const* d_in, const int* in_sizes, int n_in,
                              void* d_out, int out_size, void* d_ws, size_t ws_size,
                              hipStream_t stream) {
    const float* x   = (const float*)d_in[0];
    const int*  eidx = (const int*)d_in[1];
    const float* W0 = (const float*)d_in[3];  const float* b0 = (const float*)d_in[4];
    const float* Wc1= (const float*)d_in[5];  const float* as1= (const float*)d_in[6];
    const float* ad1= (const float*)d_in[7];  const float* bc1= (const float*)d_in[8];
    const float* Wc2= (const float*)d_in[9];  const float* as2= (const float*)d_in[10];
    const float* ad2= (const float*)d_in[11]; const float* bc2= (const float*)d_in[12];
    const float* Wc3= (const float*)d_in[13]; const float* as3= (const float*)d_in[14];
    const float* ad3= (const float*)d_in[15]; const float* bc3= (const float*)d_in[16];
    const float* W1 = (const float*)d_in[17]; const float* b1 = (const float*)d_in[18];
    const float* W2 = (const float*)d_in[19]; const float* b2 = (const float*)d_in[20];
    float* out = (float*)d_out;

    const int N  = in_sizes[0]/24;
    const int E  = in_sizes[1]/2;
    const int ET = E + N;

    char* w = (char*)d_ws;
    size_t off = 0;
    auto alloc = [&](size_t bytes)->void* {
        void* p = w + off;
        off = (off + bytes + 255) & ~(size_t)255;
        return p;
    };
    int*   cnt    = (int*)  alloc((size_t)N*4);
    int*   indptr = (int*)  alloc((size_t)(N+1)*4);
    int*   srcs   = (int*)  alloc((size_t)ET*4);
    int*   rng    = (int*)  alloc((size_t)N*8*4);
    float* es     = (float*)alloc((size_t)N*NHEADS*4);
    float* ed     = (float*)alloc((size_t)N*NHEADS*4);
    float* wbuf   = (float*)alloc((size_t)ET*NHEADS*4);
    float* nfA    = (float*)alloc((size_t)N*256*4);
    float* nfB    = (float*)alloc((size_t)N*256*4);
    ushort_t* hf  = (ushort_t*)alloc((size_t)N*1280*2);
    ushort_t* part= (ushort_t*)alloc((size_t)8*N*128*2);
    ushort_t* WT1 = (ushort_t*)alloc((size_t)320*32*2);
    ushort_t* WT2 = (ushort_t*)alloc((size_t)640*32*2);
    ushort_t* WT3 = (ushort_t*)alloc((size_t)1280*64*2);
    ushort_t* WT4 = (ushort_t*)alloc((size_t)256*128*2);

    // weight transposes (bf16, k-padded), single dispatch
    k_trans_all<<<(145408+255)/256,256,0,stream>>>(Wc1, Wc2, Wc3, W1, WT1, WT2, WT3, WT4);

    // CSR by dst (+ sorted src lists + range boundaries)
    hipMemsetAsync(cnt, 0, (size_t)N*4, stream);
    int gE = (ET+255)/256;
    k_count<<<gE,256,0,stream>>>(eidx, E, N, cnt);
    k_scan <<<1,1024,0,stream>>>(cnt, N, ET, indptr);
    k_fill <<<gE,256,0,stream>>>(eidx, E, N, cnt, srcs);
    k_sortw<<<((size_t)N*64+255)/256,256,0,stream>>>(indptr, srcs, rng, N);

    int gA    = (N*NHEADS*4+255)/256;
    int gRow  = (N+63)/64;
    int gNode = (N+3)/4;
    int gGath = ((N+3)/4)*8;

    // fc0
    k_fc0<<<(N*16+255)/256,256,0,stream>>>(x, W0, b0, nfA, N);

    // GAT1: 16 -> H x 32
    k_gemm<16,32,0,1><<<dim3(gRow,320/64),256,0,stream>>>(nfA, WT1, nullptr, hf, N, 320);
    k_attn<32><<<gA,256,0,stream>>>(hf, as1, ad1, es, ed, N);
    k_wts<<<gNode,256,0,stream>>>(indptr, srcs, es, ed, wbuf, N);
    k_gath<32><<<gGath,256,0,stream>>>(indptr, srcs, rng, wbuf, hf, part, N);
    k_red<32><<<(N*4+255)/256,256,0,stream>>>(part, bc1, nfB, N);

    // GAT2: 32 -> H x 64
    k_gemm<32,32,0,1><<<dim3(gRow,640/64),256,0,stream>>>(nfB, WT2, nullptr, hf, N, 640);
    k_attn<64><<<gA,256,0,stream>>>(hf, as2, ad2, es, ed, N);
    k_wts<<<gNode,256,0,stream>>>(indptr, srcs, es, ed, wbuf, N);
    k_gath<64><<<gGath,256,0,stream>>>(indptr, srcs, rng, wbuf, hf, part, N);
    k_red<64><<<(N*8+255)/256,256,0,stream>>>(part, bc2, nfA, N);

    // GAT3: 64 -> H x 128
    k_gemm<64,64,0,1><<<dim3(gRow,1280/64),256,0,stream>>>(nfA, WT3, nullptr, hf, N, 1280);
    k_attn<128><<<gA,256,0,stream>>>(hf, as3, ad3, es, ed, N);
    k_wts<<<gNode,256,0,stream>>>(indptr, srcs, es, ed, wbuf, N);
    k_gath<128><<<gGath,256,0,stream>>>(indptr, srcs, rng, wbuf, hf, part, N);
    k_red<128><<<(N*16+255)/256,256,0,stream>>>(part, bc3, nfB, N);

    // fc1: [N,128]@[128,256] + bias + ELU (f32 out)
    k_gemm<128,128,1,0><<<dim3(gRow,256/64),256,0,stream>>>(nfB, WT4, b1, nfA, N, 256);
    // head
    k_head<<<(N+7)/8,256,0,stream>>>(nfA, W2, b2, out, N);
}